// Round 1
// baseline (779.700 us; speedup 1.0000x reference)
//
#include <hip/hip_runtime.h>
#include <math.h>

#define KN     20
#define DMEMC  256
#define DNC    128
#define DTC    128
#define DEC    128
#define DEMBC  128
#define NBINSC 300
#define MPB    4    // sources per block

__global__ __launch_bounds__(256) void graph_emb_kernel(
    const float* __restrict__ node_features,   // [N, 128]
    const float* __restrict__ edge_features,   // [E, 128]
    const float* __restrict__ memory_,         // [N, 256]
    const float* __restrict__ interval_table,  // [300, 128]
    const float* __restrict__ bin_boundaries,  // [301]
    const float* __restrict__ time_w,          // [128]
    const float* __restrict__ time_b,          // [128]
    const float* __restrict__ W_agg,           // [256, 256]
    const float* __restrict__ timestamps,      // [B]
    const float* __restrict__ edge_times,      // [B, K]
    const float* __restrict__ intervals,       // [B]
    const float* __restrict__ nei_intervals,   // [B, K]
    const int*   __restrict__ source_nodes,    // [B]
    const int*   __restrict__ neighbors,       // [B, K]
    const int*   __restrict__ edge_idxs,       // [B, K]
    float* __restrict__ out, int B)
{
    __shared__ float s_bb[NBINSC + 1];
    __shared__ float s_feat[MPB][DMEMC];   // summed [ete | ef] message features
    __shared__ int   s_bins[MPB][KN + 1];  // [0]=source interval bin, [1..K]=neighbor bins

    const int t  = threadIdx.x;
    const int b0 = blockIdx.x * MPB;   // B == 4096, MPB divides exactly

    // stage bin boundaries in LDS
    for (int i = t; i < NBINSC + 1; i += 256) s_bb[i] = bin_boundaries[i];
    __syncthreads();

    // ---- bucketize: 84 binary searches by threads 0..83 ----
    if (t < MPB * (KN + 1)) {
        const int m = t / (KN + 1), j = t % (KN + 1);
        const int b = b0 + m;
        const float x = (j == 0) ? intervals[b] : nei_intervals[b * KN + (j - 1)];
        // lower_bound: first i with s_bb[i] >= x  (== searchsorted side='left')
        int lo = 0, hi = NBINSC + 1;
        while (lo < hi) {
            int mid = (lo + hi) >> 1;
            if (s_bb[mid] < x) lo = mid + 1; else hi = mid;
        }
        int idx = lo - 1;
        idx = idx < 0 ? 0 : (idx > NBINSC - 1 ? NBINSC - 1 : idx);
        s_bins[m][j] = idx;
    }

    // ---- Phase A: per-dim summed message features -> LDS ----
    #pragma unroll
    for (int m = 0; m < MPB; ++m) {
        const int b = b0 + m;
        float fs = 0.f;
        if (t < DTC) {
            // time-encoder half: sum_k cos(delta_k * w_t + b_t)
            const float tsv = timestamps[b];
            const float w = time_w[t], bc = time_b[t];
            #pragma unroll
            for (int k = 0; k < KN; ++k) {
                if (neighbors[b * KN + k] != -1) {     // block-uniform branch
                    const float delta = tsv - edge_times[b * KN + k];
                    fs += cosf(fmaf(delta, w, bc));
                }
            }
        } else {
            // edge-feature half: sum_k ef[e_k][d]
            const int d = t - DTC;
            #pragma unroll
            for (int k = 0; k < KN; ++k) {
                if (neighbors[b * KN + k] != -1) {
                    const int e = edge_idxs[b * KN + k];
                    fs += edge_features[e * DEC + d];
                }
            }
        }
        s_feat[m][t] = fs;
    }
    __syncthreads();

    // ---- Phase B: src0 + mean neighbor embedding (gathers), per (m, t) ----
    float res[MPB];
    float cnt_m[MPB];
    #pragma unroll
    for (int m = 0; m < MPB; ++m) {
        const int b = b0 + m;
        const int src = source_nodes[b];
        float v = memory_[src * DMEMC + t];
        if (t < DNC) v += node_features[src * DNC + t];
        else         v += interval_table[s_bins[m][0] * DEMBC + (t - DNC)];

        float nbacc = 0.f;
        float cnt = 0.f;
        #pragma unroll
        for (int k = 0; k < KN; ++k) {
            const int nb = neighbors[b * KN + k];
            if (nb != -1) {
                cnt += 1.f;
                float x = memory_[nb * DMEMC + t];
                if (t < DNC) x += node_features[nb * DNC + t];
                else         x += interval_table[s_bins[m][k + 1] * DEMBC + (t - DNC)];
                nbacc += x;
            }
        }
        cnt = fmaxf(cnt, 1.f);
        cnt_m[m] = cnt;
        res[m] = v + nbacc / cnt;
    }

    // ---- Phase C: msg matmul  out_d += (feat_sum @ W_agg)[d] / cnt ----
    float acc[MPB] = {0.f, 0.f, 0.f, 0.f};
    for (int f = 0; f < DMEMC; ++f) {
        const float w = W_agg[f * DMEMC + t];   // coalesced; L2-resident
        #pragma unroll
        for (int m = 0; m < MPB; ++m) acc[m] += s_feat[m][f] * w;
    }

    #pragma unroll
    for (int m = 0; m < MPB; ++m) {
        out[(b0 + m) * DMEMC + t] = res[m] + acc[m] / cnt_m[m];
    }
}

extern "C" void kernel_launch(void* const* d_in, const int* in_sizes, int n_in,
                              void* d_out, int out_size, void* d_ws, size_t ws_size,
                              hipStream_t stream) {
    const float* node_features  = (const float*)d_in[0];
    const float* edge_features  = (const float*)d_in[1];
    const float* memory_        = (const float*)d_in[2];
    const float* interval_table = (const float*)d_in[3];
    const float* bin_boundaries = (const float*)d_in[4];
    const float* time_w         = (const float*)d_in[5];
    const float* time_b         = (const float*)d_in[6];
    const float* W_agg          = (const float*)d_in[7];
    const float* timestamps     = (const float*)d_in[8];
    const float* edge_times     = (const float*)d_in[9];
    const float* intervals      = (const float*)d_in[10];
    const float* nei_intervals  = (const float*)d_in[11];
    const int*   source_nodes   = (const int*)d_in[12];
    const int*   neighbors      = (const int*)d_in[13];
    const int*   edge_idxs      = (const int*)d_in[14];
    float* out = (float*)d_out;

    const int B = in_sizes[8];               // timestamps: [B]
    const int grid = (B + MPB - 1) / MPB;    // B=4096 -> 1024 blocks
    graph_emb_kernel<<<grid, 256, 0, stream>>>(
        node_features, edge_features, memory_, interval_table, bin_boundaries,
        time_w, time_b, W_agg, timestamps, edge_times, intervals, nei_intervals,
        source_nodes, neighbors, edge_idxs, out, B);
}

// Round 2
// 743.294 us; speedup vs baseline: 1.0490x; 1.0490x over previous
//
#include <hip/hip_runtime.h>
#include <math.h>

#define KN     20
#define DMEMC  256
#define DNC    128
#define DEC    128
#define DEMBC  128
#define NBINSC 300
#define MPB    4    // sources per block: wave w handles source b0+w

__device__ __forceinline__ float4 ld4(const float* p) {
    return *reinterpret_cast<const float4*>(p);
}

__global__ __launch_bounds__(256) void graph_emb_kernel(
    const float* __restrict__ node_features,   // [N, 128]
    const float* __restrict__ edge_features,   // [E, 128]
    const float* __restrict__ memory_,         // [N, 256]
    const float* __restrict__ interval_table,  // [300, 128]
    const float* __restrict__ bin_boundaries,  // [301]
    const float* __restrict__ time_w,          // [128]
    const float* __restrict__ time_b,          // [128]
    const float* __restrict__ W_agg,           // [256, 256]
    const float* __restrict__ timestamps,      // [B]
    const float* __restrict__ edge_times,      // [B, K]
    const float* __restrict__ intervals,       // [B]
    const float* __restrict__ nei_intervals,   // [B, K]
    const int*   __restrict__ source_nodes,    // [B]
    const int*   __restrict__ neighbors,       // [B, K]
    const int*   __restrict__ edge_idxs,       // [B, K]
    float* __restrict__ out, int B)
{
    __shared__ float s_bb[NBINSC + 1];
    __shared__ __align__(16) float s_feat[MPB][DMEMC]; // summed [ete|ef] msg feats, pre-scaled 1/cnt
    __shared__ __align__(16) float s_res[MPB][DMEMC];  // src0 + mean neighbor emb
    __shared__ int s_bins[MPB][KN + 1];

    const int t  = threadIdx.x;
    const int w  = t >> 6;          // wave id = which source of the 4
    const int l  = t & 63;          // lane
    const int b0 = blockIdx.x * MPB;
    const int b  = b0 + w;

    for (int i = t; i <= NBINSC; i += 256) s_bb[i] = bin_boundaries[i];
    __syncthreads();

    // ---- bucketize: lanes 0..20 of each wave do 21 binary searches ----
    if (l <= KN && b < B) {
        const float x = (l == 0) ? intervals[b] : nei_intervals[b * KN + (l - 1)];
        int lo = 0, hi = NBINSC + 1;           // lower_bound over s_bb[0..300]
        while (lo < hi) {
            int mid = (lo + hi) >> 1;
            if (s_bb[mid] < x) lo = mid + 1; else hi = mid;
        }
        int idx = lo - 1;
        idx = idx < 0 ? 0 : (idx > NBINSC - 1 ? NBINSC - 1 : idx);
        s_bins[w][l] = idx;
    }
    __syncthreads();

    if (b < B) {
        // valid count (neighbors uniform per wave -> scalar loads)
        float cnt = 0.f;
        #pragma unroll
        for (int k = 0; k < KN; ++k) cnt += (neighbors[b * KN + k] != -1) ? 1.f : 0.f;
        const float inv = 1.f / fmaxf(cnt, 1.f);

        const int d0 = 4 * l;                  // this lane's 4 output dims

        // ---- Phase B: src0 + mean neighbor embedding, float4 per lane ----
        const long src = source_nodes[b];
        float4 v = ld4(memory_ + src * DMEMC + d0);
        if (l < 32) {
            float4 a = ld4(node_features + src * DNC + d0);
            v.x += a.x; v.y += a.y; v.z += a.z; v.w += a.w;
        } else {
            float4 a = ld4(interval_table + (long)s_bins[w][0] * DEMBC + (d0 - 128));
            v.x += a.x; v.y += a.y; v.z += a.z; v.w += a.w;
        }
        float4 nb4 = make_float4(0.f, 0.f, 0.f, 0.f);
        #pragma unroll
        for (int k = 0; k < KN; ++k) {
            const int nb = neighbors[b * KN + k];
            if (nb != -1) {
                float4 x = ld4(memory_ + (long)nb * DMEMC + d0);
                float4 a;
                if (l < 32) a = ld4(node_features + (long)nb * DNC + d0);
                else        a = ld4(interval_table + (long)s_bins[w][k + 1] * DEMBC + (d0 - 128));
                nb4.x += x.x + a.x; nb4.y += x.y + a.y;
                nb4.z += x.z + a.z; nb4.w += x.w + a.w;
            }
        }
        float4 r = make_float4(v.x + nb4.x * inv, v.y + nb4.y * inv,
                               v.z + nb4.z * inv, v.w + nb4.w * inv);
        *reinterpret_cast<float4*>(&s_res[w][d0]) = r;

        // ---- Phase A: summed message features [ete | ef], float4 per lane ----
        float4 fs = make_float4(0.f, 0.f, 0.f, 0.f);
        if (l < 32) {
            // time-encoder dims d0..d0+3
            const float4 w4 = ld4(time_w + d0);
            const float4 c4 = ld4(time_b + d0);
            const float ts = timestamps[b];
            #pragma unroll
            for (int k = 0; k < KN; ++k) {
                if (neighbors[b * KN + k] != -1) {
                    const float dlt = ts - edge_times[b * KN + k];
                    fs.x += __cosf(fmaf(dlt, w4.x, c4.x));
                    fs.y += __cosf(fmaf(dlt, w4.y, c4.y));
                    fs.z += __cosf(fmaf(dlt, w4.z, c4.z));
                    fs.w += __cosf(fmaf(dlt, w4.w, c4.w));
                }
            }
        } else {
            // edge-feature dims (d0-128)..(d0-125)
            const int e0 = d0 - 128;
            #pragma unroll
            for (int k = 0; k < KN; ++k) {
                if (neighbors[b * KN + k] != -1) {
                    const long e = edge_idxs[b * KN + k];
                    float4 a = ld4(edge_features + e * DEC + e0);
                    fs.x += a.x; fs.y += a.y; fs.z += a.z; fs.w += a.w;
                }
            }
        }
        fs.x *= inv; fs.y *= inv; fs.z *= inv; fs.w *= inv;
        *reinterpret_cast<float4*>(&s_feat[w][d0]) = fs;
    }
    __syncthreads();

    // ---- Phase C: out_d = res_d + (feat/cnt) @ W_agg[:,d]  (block-cooperative,
    //      W_agg read once per block, L2-resident) ----
    float a0 = 0.f, a1 = 0.f, a2 = 0.f, a3 = 0.f;
    for (int f = 0; f < DMEMC; ++f) {
        const float wv = W_agg[f * DMEMC + t];   // coalesced dword per lane
        a0 = fmaf(s_feat[0][f], wv, a0);
        a1 = fmaf(s_feat[1][f], wv, a1);
        a2 = fmaf(s_feat[2][f], wv, a2);
        a3 = fmaf(s_feat[3][f], wv, a3);
    }
    if (b0 + 0 < B) out[(long)(b0 + 0) * DMEMC + t] = s_res[0][t] + a0;
    if (b0 + 1 < B) out[(long)(b0 + 1) * DMEMC + t] = s_res[1][t] + a1;
    if (b0 + 2 < B) out[(long)(b0 + 2) * DMEMC + t] = s_res[2][t] + a2;
    if (b0 + 3 < B) out[(long)(b0 + 3) * DMEMC + t] = s_res[3][t] + a3;
}

extern "C" void kernel_launch(void* const* d_in, const int* in_sizes, int n_in,
                              void* d_out, int out_size, void* d_ws, size_t ws_size,
                              hipStream_t stream) {
    const float* node_features  = (const float*)d_in[0];
    const float* edge_features  = (const float*)d_in[1];
    const float* memory_        = (const float*)d_in[2];
    const float* interval_table = (const float*)d_in[3];
    const float* bin_boundaries = (const float*)d_in[4];
    const float* time_w         = (const float*)d_in[5];
    const float* time_b         = (const float*)d_in[6];
    const float* W_agg          = (const float*)d_in[7];
    const float* timestamps     = (const float*)d_in[8];
    const float* edge_times     = (const float*)d_in[9];
    const float* intervals      = (const float*)d_in[10];
    const float* nei_intervals  = (const float*)d_in[11];
    const int*   source_nodes   = (const int*)d_in[12];
    const int*   neighbors      = (const int*)d_in[13];
    const int*   edge_idxs      = (const int*)d_in[14];
    float* out = (float*)d_out;

    const int B = in_sizes[8];               // timestamps: [B]
    const int grid = (B + MPB - 1) / MPB;    // B=4096 -> 1024 blocks
    graph_emb_kernel<<<grid, 256, 0, stream>>>(
        node_features, edge_features, memory_, interval_table, bin_boundaries,
        time_w, time_b, W_agg, timestamps, edge_times, intervals, nei_intervals,
        source_nodes, neighbors, edge_idxs, out, B);
}